// Round 4
// baseline (402.252 us; speedup 1.0000x reference)
//
#include <hip/hip_runtime.h>
#include <hip/hip_cooperative_groups.h>

namespace cg = cooperative_groups;

#define NN 19        // nodes
#define NT 4096
#define LAT 512
#define HID 2048
#define NE 342       // edges

// LDS layout (floats)
#define LDS_F    4416
#define SA_OFF   0      // sA: up to 128*21 = 2688
#define SZ_OFF   2688   // sZ: up to 64*21 = 1344 (aliased by cnt[] during M build)
#define M_OFF    4032   // M: 361
#define FLAG_OFF 4400   // i64-detect flag (int)

// ---------------------------------------------------------------------------
// Build M = I + adjacency-count (19x19) in LDS from edge_idx. Edge buffer may
// be int64 (pairs of int32) or int32; detected via odd-word check (values in
// [0,19) => int64 high words are all zero).
// ---------------------------------------------------------------------------
__device__ __forceinline__ void build_M(const int* __restrict__ ei, float* lds, int t) {
    float* M = lds + M_OFF;
    int* cnt = (int*)(lds + SZ_OFF);
    int* flag = (int*)(lds + FLAG_OFF);
    if (t == 0) *flag = 0;
    for (int i = t; i < NN * NN; i += 256) cnt[i] = 0;
    __syncthreads();
    int f = 0;
    for (int i = t; i < NE; i += 256) f |= ei[2 * i + 1];
    if (f) atomicOr(flag, 1);
    __syncthreads();
    const bool i64 = (*flag == 0);
    for (int i = t; i < NE; i += 256) {
        const int s = i64 ? ei[2 * i] : ei[i];
        const int d = i64 ? ei[2 * NE + 2 * i] : ei[NE + i];
        atomicAdd(&cnt[d * NN + s], 1);
    }
    __syncthreads();
    for (int i = t; i < NN * NN; i += 256)
        M[i] = (float)cnt[i] + ((i / NN) == (i % NN) ? 1.f : 0.f);
    __syncthreads();
}

// ---------------------------------------------------------------------------
// GEMM inner: acc[19][4cols] over a BK k-slice staged in sA[k][i] (stride 21).
// float4 weight loads, 8 in flight (128 B/lane).
// ---------------------------------------------------------------------------
template <int BK, int N>
__device__ __forceinline__ void gemm_inner(int t, int kc, int cb,
                                           const float* __restrict__ W,
                                           float* __restrict__ part,
                                           const float* __restrict__ sA) {
    const int k0 = kc * BK;
    const int col = cb * 1024 + 4 * t;
    const float4* __restrict__ w = (const float4*)(W + (size_t)k0 * N + col);
    float4 acc[NN];
#pragma unroll
    for (int i = 0; i < NN; ++i) acc[i] = make_float4(0.f, 0.f, 0.f, 0.f);
#pragma unroll 1
    for (int kk = 0; kk < BK; kk += 8) {
        float4 wb[8];
#pragma unroll
        for (int u = 0; u < 8; ++u) wb[u] = w[(size_t)(kk + u) * (N / 4)];
#pragma unroll
        for (int u = 0; u < 8; ++u) {
#pragma unroll
            for (int i = 0; i < NN; ++i) {
                const float av = sA[(kk + u) * 21 + i];
                acc[i].x = fmaf(av, wb[u].x, acc[i].x);
                acc[i].y = fmaf(av, wb[u].y, acc[i].y);
                acc[i].z = fmaf(av, wb[u].z, acc[i].z);
                acc[i].w = fmaf(av, wb[u].w, acc[i].w);
            }
        }
    }
    float* __restrict__ p = part + (size_t)kc * NN * N + col;
#pragma unroll
    for (int i = 0; i < NN; ++i) *(float4*)(p + (size_t)i * N) = acc[i];
}

// plain: stage A[19][K] k-slice directly into sA
template <int BK, int K, int N>
__device__ __forceinline__ void gemm_plain(int bid, int t, const float* __restrict__ A,
                                           const float* __restrict__ W,
                                           float* __restrict__ part, float* lds) {
    const int NCB = N / 1024;
    const int kc = bid / NCB, cb = bid % NCB;
    const int k0 = kc * BK;
    float* sA = lds + SA_OFF;
    for (int idx = t; idx < NN * BK; idx += 256) {
        const int i = idx / BK, c = idx % BK;
        sA[c * 21 + i] = A[(size_t)i * K + k0 + c];
    }
    __syncthreads();
    gemm_inner<BK, N>(t, kc, cb, W, part, sA);
    __syncthreads();
}

// fused GIN-agg: stage Asrc k-slice, then sA = M @ slice (aggregation folded in)
template <int BK, int K, int N>
__device__ __forceinline__ void gemm_from_M(int bid, int t, const float* __restrict__ Asrc,
                                            const float* __restrict__ W,
                                            float* __restrict__ part, float* lds,
                                            const int* __restrict__ ei) {
    const int NCB = N / 1024;
    const int kc = bid / NCB, cb = bid % NCB;
    const int k0 = kc * BK;
    build_M(ei, lds, t);
    float* sA = lds + SA_OFF;
    float* sZ = lds + SZ_OFF;
    float* M = lds + M_OFF;
    for (int idx = t; idx < NN * BK; idx += 256) {
        const int s = idx / BK, c = idx % BK;
        sZ[c * 21 + s] = Asrc[(size_t)s * K + k0 + c];
    }
    __syncthreads();
    for (int idx = t; idx < NN * BK; idx += 256) {
        const int i = idx / BK, c = idx % BK;
        float acc = 0.f;
#pragma unroll
        for (int s = 0; s < NN; ++s) acc = fmaf(M[i * NN + s], sZ[c * 21 + s], acc);
        sA[c * 21 + i] = acc;
    }
    __syncthreads();
    gemm_inner<BK, N>(t, kc, cb, W, part, sA);
    __syncthreads();
}

// reduce split-K partials + bias (+ optional relu) -> [19][N] float4
__device__ __forceinline__ void reduce_stage(int bid, int t, const float* __restrict__ part,
                                             const float* __restrict__ bias,
                                             float* __restrict__ outp,
                                             int N4, int nchunk, bool relu) {
    const int idx = bid * 256 + t;
    if (idx < NN * N4) {
        const int i = idx / N4, n4 = idx % N4;
        float4 s = ((const float4*)bias)[n4];
        const float4* __restrict__ p = (const float4*)part + (size_t)i * N4 + n4;
        for (int c = 0; c < nchunk; ++c) {
            const float4 v = p[(size_t)c * NN * N4];
            s.x += v.x; s.y += v.y; s.z += v.z; s.w += v.w;
        }
        if (relu) {
            s.x = s.x > 0.f ? s.x : 0.f;
            s.y = s.y > 0.f ? s.y : 0.f;
            s.z = s.z > 0.f ? s.z : 0.f;
            s.w = s.w > 0.f ? s.w : 0.f;
        }
        ((float4*)outp)[(size_t)i * N4 + n4] = s;
    }
}

// same, scalar stores into d_out+1 (only 4B-aligned)
__device__ __forceinline__ void reduce_out_stage(int bid, int t, const float* __restrict__ part,
                                                 const float* __restrict__ bias,
                                                 float* __restrict__ outp,
                                                 int N4, int nchunk) {
    const int idx = bid * 256 + t;
    if (idx < NN * N4) {
        const int i = idx / N4, n4 = idx % N4;
        float4 s = ((const float4*)bias)[n4];
        const float4* __restrict__ p = (const float4*)part + (size_t)i * N4 + n4;
        for (int c = 0; c < nchunk; ++c) {
            const float4 v = p[(size_t)c * NN * N4];
            s.x += v.x; s.y += v.y; s.z += v.z; s.w += v.w;
        }
        float* __restrict__ o = outp + ((size_t)i * N4 + n4) * 4;
        o[0] = s.x; o[1] = s.y; o[2] = s.z; o[3] = s.w;
    }
}

// classifier partial: chunk bid of flat[77824] @ Wc1[77824,512]; BK=304
__device__ __forceinline__ void cls_stage(int bid, int t, const float* __restrict__ flat,
                                          const float* __restrict__ Wc1,
                                          float* __restrict__ part, float* lds) {
    const int q = t & 127, kp = t >> 7;
    const int k0 = bid * 304;
    const float4* __restrict__ w = (const float4*)Wc1 + (size_t)k0 * 128 + q;
    const float* __restrict__ f = flat + k0;
    float4 acc = make_float4(0.f, 0.f, 0.f, 0.f);
#pragma unroll 1
    for (int k = kp; k < 304; k += 16) {
        float4 wb[8];
        float fv[8];
#pragma unroll
        for (int u = 0; u < 8; ++u) wb[u] = w[(size_t)(k + 2 * u) * 128];
#pragma unroll
        for (int u = 0; u < 8; ++u) fv[u] = f[k + 2 * u];
#pragma unroll
        for (int u = 0; u < 8; ++u) {
            acc.x = fmaf(fv[u], wb[u].x, acc.x);
            acc.y = fmaf(fv[u], wb[u].y, acc.y);
            acc.z = fmaf(fv[u], wb[u].z, acc.z);
            acc.w = fmaf(fv[u], wb[u].w, acc.w);
        }
    }
    float4* comb = (float4*)lds;
    __syncthreads();
    if (kp) comb[q] = acc;
    __syncthreads();
    if (!kp) {
        const float4 o = comb[q];
        acc.x += o.x; acc.y += o.y; acc.z += o.z; acc.w += o.w;
        ((float4*)part)[(size_t)bid * 128 + q] = acc;
    }
}

// ---------------------------------------------------------------------------
// One persistent cooperative kernel: 256 blocks x 256 threads.
// ---------------------------------------------------------------------------
__global__ void __launch_bounds__(256, 2)
fused_gnn(const float* __restrict__ z, const int* __restrict__ ei,
          const float* __restrict__ W1a, const float* __restrict__ b1a,
          const float* __restrict__ W1b, const float* __restrict__ b1b,
          const float* __restrict__ W2a, const float* __restrict__ b2a,
          const float* __restrict__ W2b, const float* __restrict__ b2b,
          const float* __restrict__ Wc1, const float* __restrict__ bc1,
          const float* __restrict__ Wc2, const float* __restrict__ bc2,
          float* __restrict__ out, float* __restrict__ ws) {
    cg::grid_group grid = cg::this_grid();
    __shared__ __align__(16) float lds[LDS_F];
    const int t = threadIdx.x;
    const int bid = blockIdx.x;

    float* h1a   = ws + 16384;    // 19*2048
    float* h1r   = ws + 65536;    // 19*2048
    float* t2    = ws + 163840;   // 19*4096
    float* part  = ws + 262144;   // up to 64*19*4096 = 4,980,736
    float* part2 = ws + 5242880;  // 16*512

    // S1: part = (M@z) @ W1a   [K=512, BK=32: 16kc x 2cb = 32 blocks]
    if (bid < 32) gemm_from_M<32, LAT, HID>(bid, t, z, W1a, part, lds, ei);
    grid.sync();
    // S2: h1a = relu(reduce(16) + b1a)   [38 blocks]
    if (bid < 38) reduce_stage(bid, t, part, b1a, h1a, HID / 4, 16, true);
    grid.sync();
    // S3: part = h1a @ W1b   [K=2048, BK=32: 64kc x 2cb = 128 blocks]
    if (bid < 128) gemm_plain<32, HID, HID>(bid, t, h1a, W1b, part, lds);
    grid.sync();
    // S4: h1r = relu(reduce(64) + b1b)   (inter-layer relu)
    if (bid < 38) reduce_stage(bid, t, part, b1b, h1r, HID / 4, 64, true);
    grid.sync();
    // S5: part = (M@h1r) @ W2a   [K=2048, BK=32: 64kc x 4cb = 256 blocks]
    gemm_from_M<32, HID, NT>(bid, t, h1r, W2a, part, lds, ei);
    grid.sync();
    // S6: t2 = relu(reduce(64) + b2a)   [76 blocks]
    if (bid < 76) reduce_stage(bid, t, part, b2a, t2, NT / 4, 64, true);
    grid.sync();
    // S7: part = t2 @ W2b   [K=4096, BK=64: 64kc x 4cb = 256 blocks]
    gemm_plain<64, NT, NT>(bid, t, t2, W2b, part, lds);
    grid.sync();
    // S8: out[1..] = reduce(64) + b2b   [76 blocks]
    if (bid < 76) reduce_out_stage(bid, t, part, b2b, out + 1, NT / 4, 64);
    grid.sync();
    // S9: classifier partials: 256 chunks of BK=304 (77824 = 256*304)
    cls_stage(bid, t, out + 1, Wc1, part, lds);
    grid.sync();
    // S10: part2[g][512] = sum of 16 chunks   [16 blocks]
    if (bid < 16) {
        float2 s = make_float2(0.f, 0.f);
#pragma unroll
        for (int c = 0; c < 16; ++c) {
            const float2 v = *(const float2*)(part + (size_t)(bid * 16 + c) * LAT + 2 * t);
            s.x += v.x; s.y += v.y;
        }
        *(float2*)(part2 + (size_t)bid * LAT + 2 * t) = s;
    }
    grid.sync();
    // S11: final dot + sigmoid   [block 0]
    if (bid == 0) {
        float2 s = make_float2(bc1[2 * t], bc1[2 * t + 1]);
#pragma unroll
        for (int g = 0; g < 16; ++g) {
            const float2 v = *(const float2*)(part2 + (size_t)g * LAT + 2 * t);
            s.x += v.x; s.y += v.y;
        }
        float r = s.x * Wc2[2 * t] + s.y * Wc2[2 * t + 1];
        float* red = lds;
        red[t] = r;
        __syncthreads();
        for (int off = 128; off > 0; off >>= 1) {
            if (t < off) red[t] += red[t + off];
            __syncthreads();
        }
        if (t == 0) out[0] = 1.f / (1.f + expf(-(red[0] + bc2[0])));
    }
}

extern "C" void kernel_launch(void* const* d_in, const int* in_sizes, int n_in,
                              void* d_out, int out_size, void* d_ws, size_t ws_size,
                              hipStream_t stream) {
    const float* z   = (const float*)d_in[0];
    const int*   ei  = (const int*)d_in[1];
    const float* W1a = (const float*)d_in[2];
    const float* b1a = (const float*)d_in[3];
    const float* W1b = (const float*)d_in[4];
    const float* b1b = (const float*)d_in[5];
    const float* W2a = (const float*)d_in[6];
    const float* b2a = (const float*)d_in[7];
    const float* W2b = (const float*)d_in[8];
    const float* b2b = (const float*)d_in[9];
    const float* Wc1 = (const float*)d_in[10];
    const float* bc1 = (const float*)d_in[11];
    const float* Wc2 = (const float*)d_in[12];
    const float* bc2 = (const float*)d_in[13];
    float* out = (float*)d_out;
    float* ws  = (float*)d_ws;

    void* args[] = {&z, &ei, &W1a, &b1a, &W1b, &b1b, &W2a, &b2a, &W2b, &b2b,
                    &Wc1, &bc1, &Wc2, &bc2, &out, &ws};
    hipLaunchCooperativeKernel((void*)fused_gnn, dim3(256), dim3(256), args, 0, stream);
}

// Round 5
// 157.825 us; speedup vs baseline: 2.5487x; 2.5487x over previous
//
#include <hip/hip_runtime.h>

#define NN 19        // nodes
#define NT 4096
#define LAT 512
#define HID 2048
#define NE 342       // edges

// ---------------------------------------------------------------------------
// Build M = I + adjacency-count (19x19) into sM from edge_idx. cnt[] aliases
// scratch LDS. Edge buffer may be int64 (pairs of int32) or int32, detected
// via odd-word check (values in [0,19) => int64 high words all zero).
// ---------------------------------------------------------------------------
__device__ __forceinline__ void build_M(const int* __restrict__ ei, float* sM,
                                        int* scratch, int t) {
    int* cnt = scratch;
    int* flag = scratch + NN * NN;
    if (t == 0) *flag = 0;
    for (int i = t; i < NN * NN; i += 256) cnt[i] = 0;
    __syncthreads();
    int f = 0;
    for (int i = t; i < NE; i += 256) f |= ei[2 * i + 1];
    if (f) atomicOr(flag, 1);
    __syncthreads();
    const bool i64 = (*flag == 0);
    for (int i = t; i < NE; i += 256) {
        const int s = i64 ? ei[2 * i] : ei[i];
        const int d = i64 ? ei[2 * NE + 2 * i] : ei[NE + i];
        atomicAdd(&cnt[d * NN + s], 1);
    }
    __syncthreads();
    for (int i = t; i < NN * NN; i += 256)
        sM[i] = (float)cnt[i] + ((i / NN) == (i % NN) ? 1.f : 0.f);
    __syncthreads();
}

// ---------------------------------------------------------------------------
// GEMM inner: acc[19][4 cols] over a BK k-slice staged in sA[k*21+i].
// float4 weight loads, 8 in flight (128 B/lane). Writes partial chunk kc.
// ---------------------------------------------------------------------------
template <int BK, int N>
__device__ __forceinline__ void gemm_inner(int t, int kc, int cb,
                                           const float* __restrict__ W,
                                           float* __restrict__ part,
                                           const float* __restrict__ sA) {
    const int k0 = kc * BK;
    const int col = cb * 1024 + 4 * t;
    const float4* __restrict__ w = (const float4*)(W + (size_t)k0 * N + col);
    float4 acc[NN];
#pragma unroll
    for (int i = 0; i < NN; ++i) acc[i] = make_float4(0.f, 0.f, 0.f, 0.f);
#pragma unroll 1
    for (int kk = 0; kk < BK; kk += 8) {
        float4 wb[8];
#pragma unroll
        for (int u = 0; u < 8; ++u) wb[u] = w[(size_t)(kk + u) * (N / 4)];
#pragma unroll
        for (int u = 0; u < 8; ++u) {
#pragma unroll
            for (int i = 0; i < NN; ++i) {
                const float av = sA[(kk + u) * 21 + i];
                acc[i].x = fmaf(av, wb[u].x, acc[i].x);
                acc[i].y = fmaf(av, wb[u].y, acc[i].y);
                acc[i].z = fmaf(av, wb[u].z, acc[i].z);
                acc[i].w = fmaf(av, wb[u].w, acc[i].w);
            }
        }
    }
    float* __restrict__ p = part + (size_t)kc * NN * N + col;
#pragma unroll
    for (int i = 0; i < NN; ++i) *(float4*)(p + (size_t)i * N) = acc[i];
}

// K1: part1 = (M @ z) @ W1a.  K=512, BK=32; grid (cb=2, kc=16)
__global__ __launch_bounds__(256) void gemm_l1a(const float* __restrict__ z,
                                                const int* __restrict__ ei,
                                                const float* __restrict__ W1a,
                                                float* __restrict__ part1) {
    __shared__ __align__(16) float sA[32 * 21];
    __shared__ __align__(16) float sZ[32 * 21];
    __shared__ float sM[NN * NN];
    __shared__ int scratch[NN * NN + 1];
    const int t = threadIdx.x, cb = blockIdx.x, kc = blockIdx.y;
    const int k0 = kc * 32;
    build_M(ei, sM, scratch, t);
    for (int idx = t; idx < NN * 32; idx += 256) {
        const int s = idx / 32, c = idx % 32;
        sZ[c * 21 + s] = z[(size_t)s * LAT + k0 + c];
    }
    __syncthreads();
    for (int idx = t; idx < NN * 32; idx += 256) {
        const int i = idx / 32, c = idx % 32;
        float acc = 0.f;
#pragma unroll
        for (int s = 0; s < NN; ++s) acc = fmaf(sM[i * NN + s], sZ[c * 21 + s], acc);
        sA[c * 21 + i] = acc;
    }
    __syncthreads();
    gemm_inner<32, HID>(t, kc, cb, W1a, part1, sA);
}

// K2: part2 = relu(reduce16(part1)+b1a) @ W1b.  K=2048, BK=64; grid (2, 32)
__global__ __launch_bounds__(256) void gemm_l1b(const float* __restrict__ part1,
                                                const float* __restrict__ b1a,
                                                const float* __restrict__ W1b,
                                                float* __restrict__ part2) {
    __shared__ __align__(16) float sA[64 * 21];
    const int t = threadIdx.x, cb = blockIdx.x, kc = blockIdx.y;
    const int k0 = kc * 64;
    for (int idx = t; idx < NN * 64; idx += 256) {
        const int i = idx / 64, c = idx % 64;
        const int k = k0 + c;
        float s = b1a[k];
#pragma unroll
        for (int cc = 0; cc < 16; ++cc) s += part1[((size_t)cc * NN + i) * HID + k];
        sA[c * 21 + i] = s > 0.f ? s : 0.f;
    }
    __syncthreads();
    gemm_inner<64, HID>(t, kc, cb, W1b, part2, sA);
}

// K3: part3 = (M @ relu(reduce32(part2)+b1b)) @ W2a.  K=2048, BK=64; grid (4, 32)
__global__ __launch_bounds__(256) void gemm_l2a(const float* __restrict__ part2,
                                                const float* __restrict__ b1b,
                                                const int* __restrict__ ei,
                                                const float* __restrict__ W2a,
                                                float* __restrict__ part3) {
    __shared__ __align__(16) float sA[64 * 21];
    __shared__ __align__(16) float sZ[64 * 21];
    __shared__ float sM[NN * NN];
    __shared__ int scratch[NN * NN + 1];
    const int t = threadIdx.x, cb = blockIdx.x, kc = blockIdx.y;
    const int k0 = kc * 64;
    build_M(ei, sM, scratch, t);
    for (int idx = t; idx < NN * 64; idx += 256) {
        const int i = idx / 64, c = idx % 64;
        const int k = k0 + c;
        float s = b1b[k];
#pragma unroll
        for (int cc = 0; cc < 32; ++cc) s += part2[((size_t)cc * NN + i) * HID + k];
        sZ[c * 21 + i] = s > 0.f ? s : 0.f;
    }
    __syncthreads();
    for (int idx = t; idx < NN * 64; idx += 256) {
        const int i = idx / 64, c = idx % 64;
        float acc = 0.f;
#pragma unroll
        for (int s = 0; s < NN; ++s) acc = fmaf(sM[i * NN + s], sZ[c * 21 + s], acc);
        sA[c * 21 + i] = acc;
    }
    __syncthreads();
    gemm_inner<64, NT>(t, kc, cb, W2a, part3, sA);
}

// K4: part4 = relu(reduce32(part3)+b2a) @ W2b.  K=4096, BK=64; grid (4, 64)
__global__ __launch_bounds__(256) void gemm_l2b(const float* __restrict__ part3,
                                                const float* __restrict__ b2a,
                                                const float* __restrict__ W2b,
                                                float* __restrict__ part4) {
    __shared__ __align__(16) float sA[64 * 21];
    const int t = threadIdx.x, cb = blockIdx.x, kc = blockIdx.y;
    const int k0 = kc * 64;
    for (int idx = t; idx < NN * 64; idx += 256) {
        const int i = idx / 64, c = idx % 64;
        const int k = k0 + c;
        float s = b2a[k];
#pragma unroll
        for (int cc = 0; cc < 32; ++cc) s += part3[((size_t)cc * NN + i) * NT + k];
        sA[c * 21 + i] = s > 0.f ? s : 0.f;
    }
    __syncthreads();
    gemm_inner<64, NT>(t, kc, cb, W2b, part4, sA);
}

// K5: per block (256 blocks), k0 = bid*304:
//   flat[k0..k0+304) = reduce64(part4)+b2b  -> write to out+1 and LDS
//   then cls partial: partC[bid][512] = flat_seg @ Wc1[k0..k0+304)
__global__ __launch_bounds__(256) void cls_out(const float* __restrict__ part4,
                                               const float* __restrict__ b2b,
                                               const float* __restrict__ Wc1,
                                               float* __restrict__ out1,
                                               float* __restrict__ partC) {
    __shared__ float sF[304];
    __shared__ __align__(16) float4 comb[128];
    const int t = threadIdx.x;
    const int k0 = blockIdx.x * 304;
    for (int e = t; e < 304; e += 256) {
        const int f = k0 + e;
        const int i = f >> 12, n = f & 4095;
        float s = b2b[n];
#pragma unroll 16
        for (int cc = 0; cc < 64; ++cc) s += part4[((size_t)cc * NN + i) * NT + n];
        sF[e] = s;
        out1[f] = s;
    }
    __syncthreads();
    const int q = t & 127, kp = t >> 7;
    const float4* __restrict__ w = (const float4*)Wc1 + (size_t)k0 * 128 + q;
    float4 acc = make_float4(0.f, 0.f, 0.f, 0.f);
#pragma unroll 1
    for (int k = kp; k < 304; k += 16) {
        float4 wb[8];
        float fv[8];
#pragma unroll
        for (int u = 0; u < 8; ++u) wb[u] = w[(size_t)(k + 2 * u) * 128];
#pragma unroll
        for (int u = 0; u < 8; ++u) fv[u] = sF[k + 2 * u];
#pragma unroll
        for (int u = 0; u < 8; ++u) {
            acc.x = fmaf(fv[u], wb[u].x, acc.x);
            acc.y = fmaf(fv[u], wb[u].y, acc.y);
            acc.z = fmaf(fv[u], wb[u].z, acc.z);
            acc.w = fmaf(fv[u], wb[u].w, acc.w);
        }
    }
    if (kp) comb[q] = acc;
    __syncthreads();
    if (!kp) {
        const float4 o = comb[q];
        acc.x += o.x; acc.y += o.y; acc.z += o.z; acc.w += o.w;
        ((float4*)partC)[(size_t)blockIdx.x * 128 + q] = acc;
    }
}

// K6: 256 cls chunks -> 16 group sums
__global__ __launch_bounds__(256) void cls_reduce(const float* __restrict__ partC,
                                                  float* __restrict__ part2c) {
    const int g = blockIdx.x, t = threadIdx.x;
    float2 s = make_float2(0.f, 0.f);
#pragma unroll
    for (int c = 0; c < 16; ++c) {
        const float2 v = *(const float2*)(partC + (size_t)(g * 16 + c) * LAT + 2 * t);
        s.x += v.x; s.y += v.y;
    }
    *(float2*)(part2c + (size_t)g * LAT + 2 * t) = s;
}

// K7: final dot + sigmoid
__global__ __launch_bounds__(512) void cls_final(const float* __restrict__ part2c,
                                                 const float* __restrict__ bc1,
                                                 const float* __restrict__ Wc2,
                                                 const float* __restrict__ bc2,
                                                 float* __restrict__ out) {
    __shared__ float red[512];
    const int t = threadIdx.x;
    float s = bc1[t];
#pragma unroll
    for (int g = 0; g < 16; ++g) s += part2c[(size_t)g * LAT + t];
    red[t] = s * Wc2[t];
    __syncthreads();
    for (int off = 256; off > 0; off >>= 1) {
        if (t < off) red[t] += red[t + off];
        __syncthreads();
    }
    if (t == 0) out[0] = 1.f / (1.f + expf(-(red[0] + bc2[0])));
}

extern "C" void kernel_launch(void* const* d_in, const int* in_sizes, int n_in,
                              void* d_out, int out_size, void* d_ws, size_t ws_size,
                              hipStream_t stream) {
    const float* z   = (const float*)d_in[0];
    const int*   ei  = (const int*)d_in[1];
    const float* W1a = (const float*)d_in[2];
    const float* b1a = (const float*)d_in[3];
    const float* W1b = (const float*)d_in[4];
    const float* b1b = (const float*)d_in[5];
    const float* W2a = (const float*)d_in[6];
    const float* b2a = (const float*)d_in[7];
    const float* W2b = (const float*)d_in[8];
    const float* b2b = (const float*)d_in[9];
    const float* Wc1 = (const float*)d_in[10];
    const float* bc1 = (const float*)d_in[11];
    const float* Wc2 = (const float*)d_in[12];
    const float* bc2 = (const float*)d_in[13];
    float* out = (float*)d_out;
    float* ws  = (float*)d_ws;

    // workspace layout (float offsets)
    float* part1  = ws + 262144;    // 16*19*2048  =   622,592
    float* part2  = ws + 1048576;   // 32*19*2048  = 1,245,184
    float* part3  = ws + 2359296;   // 32*19*4096  = 2,490,368
    float* part4  = ws + 4980736;   // 64*19*4096  = 4,980,736
    float* partC  = ws + 10485760;  // 256*512     =   131,072
    float* part2c = ws + 10616832;  // 16*512      =     8,192

    gemm_l1a<<<dim3(2, 16), 256, 0, stream>>>(z, ei, W1a, part1);
    gemm_l1b<<<dim3(2, 32), 256, 0, stream>>>(part1, b1a, W1b, part2);
    gemm_l2a<<<dim3(4, 32), 256, 0, stream>>>(part2, b1b, ei, W2a, part3);
    gemm_l2b<<<dim3(4, 64), 256, 0, stream>>>(part3, b2a, W2b, part4);
    cls_out<<<256, 256, 0, stream>>>(part4, b2b, Wc1, out + 1, partC);
    cls_reduce<<<16, 256, 0, stream>>>(partC, part2c);
    cls_final<<<1, 512, 0, stream>>>(part2c, bc1, Wc2, bc2, out);
}